// Round 1
// baseline (313.118 us; speedup 1.0000x reference)
//
#include <hip/hip_runtime.h>
#include <hip/hip_bf16.h>
#include <stdint.h>

// BitLinear: y = (int8(x) @ unpack2bit(Wp)^T) * amax/(127*ws) + bias
// M=16384 tokens, K=2048, N=2048. Integer GEMM via mfma_i32_16x16x64_i8.

typedef __attribute__((ext_vector_type(4))) int int4v;

#define GLOBAL_AS __attribute__((address_space(1)))
#define LDS_AS    __attribute__((address_space(3)))

static constexpr int MK = 2048;   // K (inner dim)
static constexpr int NN = 2048;   // out features
static constexpr int MM = 16384;  // tokens

// ---------------- activation quant: one block per token row ----------------
__global__ void quant_kernel(const float* __restrict__ x,
                             const float* __restrict__ wscale,
                             signed char* __restrict__ xq,
                             float* __restrict__ rf) {
    const int m = blockIdx.x;
    const int t = threadIdx.x;
    const float4* xr = (const float4*)(x + (size_t)m * MK);  // 512 float4/row
    float4 v0 = xr[t];
    float4 v1 = xr[t + 256];
    float amax = fmaxf(fmaxf(fabsf(v0.x), fabsf(v0.y)),
                       fmaxf(fabsf(v0.z), fabsf(v0.w)));
    amax = fmaxf(amax, fmaxf(fmaxf(fabsf(v1.x), fabsf(v1.y)),
                             fmaxf(fabsf(v1.z), fabsf(v1.w))));
    // wave (64-lane) butterfly reduce
    #pragma unroll
    for (int off = 32; off >= 1; off >>= 1)
        amax = fmaxf(amax, __shfl_xor(amax, off));
    __shared__ float smax[4];
    if ((t & 63) == 0) smax[t >> 6] = amax;
    __syncthreads();
    float a0 = fmaxf(fmaxf(smax[0], smax[1]), fmaxf(smax[2], smax[3]));
    a0 = fmaxf(a0, 1e-5f);                 // clip lower bound
    const float scale = 127.0f / a0;
    if (t == 0) rf[m] = a0 / (127.0f * wscale[0]);

    auto q = [&](float f) -> int {
        float r = rintf(f * scale);        // round-half-to-even
        r = fminf(fmaxf(r, -128.0f), 127.0f);
        return (int)r;
    };
    int p0 = (q(v0.x) & 255) | ((q(v0.y) & 255) << 8) |
             ((q(v0.z) & 255) << 16) | ((q(v0.w) & 255) << 24);
    int p1 = (q(v1.x) & 255) | ((q(v1.y) & 255) << 8) |
             ((q(v1.z) & 255) << 16) | ((q(v1.w) & 255) << 24);
    int* xqr = (int*)(xq + (size_t)m * MK);
    xqr[t]       = p0;
    xqr[t + 256] = p1;
}

// ---------------- weight unpack: [512][2048] packed -> int8 W[2048][2048] ---
// w[i*512 + r][k] = ((packed[r][k] >> 2i) & 3) - 1
__global__ void unpack_kernel(const int* __restrict__ packed,
                              signed char* __restrict__ W) {
    const int idx = blockIdx.x * 256 + threadIdx.x;   // 0 .. 512*512
    const int r  = idx >> 9;        // packed row
    const int kq = idx & 511;       // k/4
    const int4 p = ((const int4*)packed)[idx];        // 4 consecutive k
    int* Wi = (int*)W;              // 512 ints per W row
    #pragma unroll
    for (int i = 0; i < 4; i++) {
        const int sh = 2 * i;
        int b0 = ((((p.x >> sh) & 3) - 1) & 255);
        int b1 = ((((p.y >> sh) & 3) - 1) & 255);
        int b2 = ((((p.z >> sh) & 3) - 1) & 255);
        int b3 = ((((p.w >> sh) & 3) - 1) & 255);
        Wi[(i * 512 + r) * 512 + kq] = b0 | (b1 << 8) | (b2 << 16) | (b3 << 24);
    }
}

// ---------------- int8 GEMM: C[m][n] = sum_k xq[m][k]*W[n][k] --------------
// 128x128 tile, BK=64 bytes, 4 waves in 2x2, 4x4 mfma_i32_16x16x64_i8 each.
__global__ void __launch_bounds__(256)
gemm_kernel(const signed char* __restrict__ xq,   // [M][K]
            const signed char* __restrict__ W,    // [N][K]
            const float* __restrict__ rf,         // [M]
            const float* __restrict__ bias,       // [N]
            float* __restrict__ out) {            // [M][N]
    constexpr int BK = 64;
    __shared__ __attribute__((aligned(16))) unsigned char As[128 * BK];
    __shared__ __attribute__((aligned(16))) unsigned char Bs[128 * BK];

    const int tid  = threadIdx.x;
    const int wave = tid >> 6;
    const int lane = tid & 63;
    const int m0 = blockIdx.y * 128;
    const int n0 = blockIdx.x * 128;

    // staging: chunk c = 16 rows; lane i -> row c*16 + i/4, byte (i%4)*16
    const int srow  = lane >> 2;
    const int sbyte = (lane & 3) * 16;

    const int wm = (wave >> 1) * 64;   // wave's 64x64 subtile
    const int wn = (wave & 1) * 64;
    const int fr = lane & 15;          // fragment row (m or n)
    const int fk = (lane >> 4) * 16;   // fragment k byte offset

    int4v acc[4][4] = {};

    for (int k0 = 0; k0 < MK; k0 += BK) {
        #pragma unroll
        for (int c = 2 * wave; c < 2 * wave + 2; c++) {
            const signed char* ga =
                xq + (size_t)(m0 + c * 16 + srow) * MK + k0 + sbyte;
            __builtin_amdgcn_global_load_lds((const GLOBAL_AS void*)ga,
                                             (LDS_AS void*)(As + c * 1024),
                                             16, 0, 0);
            const signed char* gb =
                W + (size_t)(n0 + c * 16 + srow) * MK + k0 + sbyte;
            __builtin_amdgcn_global_load_lds((const GLOBAL_AS void*)gb,
                                             (LDS_AS void*)(Bs + c * 1024),
                                             16, 0, 0);
        }
        __syncthreads();

        int4v af[4], bf[4];
        #pragma unroll
        for (int i = 0; i < 4; i++) {
            af[i] = *(const int4v*)(As + (wm + i * 16 + fr) * BK + fk);
            bf[i] = *(const int4v*)(Bs + (wn + i * 16 + fr) * BK + fk);
        }
        #pragma unroll
        for (int mt = 0; mt < 4; mt++)
            #pragma unroll
            for (int nt = 0; nt < 4; nt++)
                acc[mt][nt] = __builtin_amdgcn_mfma_i32_16x16x64_i8(
                    af[mt], bf[nt], acc[mt][nt], 0, 0, 0);
        __syncthreads();
    }

    // epilogue: C/D map col=lane&15, row=(lane>>4)*4+reg
    const int col   = lane & 15;
    const int rbase = (lane >> 4) * 4;
    #pragma unroll
    for (int mt = 0; mt < 4; mt++) {
        #pragma unroll
        for (int r = 0; r < 4; r++) {
            const int m = m0 + wm + mt * 16 + rbase + r;
            const float rfm = rf[m];
            #pragma unroll
            for (int nt = 0; nt < 4; nt++) {
                const int n = n0 + wn + nt * 16 + col;
                out[(size_t)m * NN + n] = (float)acc[mt][nt][r] * rfm + bias[n];
            }
        }
    }
}

extern "C" void kernel_launch(void* const* d_in, const int* in_sizes, int n_in,
                              void* d_out, int out_size, void* d_ws, size_t ws_size,
                              hipStream_t stream) {
    const float* x      = (const float*)d_in[0];
    const int*   packed = (const int*)d_in[1];
    const float* wscale = (const float*)d_in[2];
    const float* bias   = (const float*)d_in[3];
    float* out = (float*)d_out;

    // workspace: xq [16384*2048] i8 | W [2048*2048] i8 | rf [16384] f32
    signed char* xq = (signed char*)d_ws;
    signed char* W  = xq + (size_t)MM * MK;
    float*       rf = (float*)(W + (size_t)NN * MK);

    quant_kernel<<<MM, 256, 0, stream>>>(x, wscale, xq, rf);
    unpack_kernel<<<(512 * 512) / 256, 256, 0, stream>>>(packed, W);
    gemm_kernel<<<dim3(NN / 128, MM / 128), 256, 0, stream>>>(xq, W, rf, bias, out);
}

// Round 2
// 312.629 us; speedup vs baseline: 1.0016x; 1.0016x over previous
//
#include <hip/hip_runtime.h>
#include <hip/hip_bf16.h>
#include <stdint.h>

// BitLinear: y = (int8(x) @ unpack2bit(Wp)^T) * amax/(127*ws) + bias
// M=16384 tokens, K=2048, N=2048. Integer GEMM via mfma_i32_16x16x64_i8.
// R2: XOR-swizzled LDS layout (chunk slot = c ^ ((row>>1)&3)) to kill the
//     8.4M LDS bank-conflict cycles seen in R1 (rows at stride 64B aliased
//     to 2 of 8 bank positions). Swizzle applied at stage-time by permuting
//     the global source chunk per lane (global_load_lds dest is lane*16).

typedef __attribute__((ext_vector_type(4))) int int4v;

#define GLOBAL_AS __attribute__((address_space(1)))
#define LDS_AS    __attribute__((address_space(3)))

static constexpr int MK = 2048;   // K (inner dim)
static constexpr int NN = 2048;   // out features
static constexpr int MM = 16384;  // tokens

// ---------------- activation quant: one block per token row ----------------
__global__ void quant_kernel(const float* __restrict__ x,
                             const float* __restrict__ wscale,
                             signed char* __restrict__ xq,
                             float* __restrict__ rf) {
    const int m = blockIdx.x;
    const int t = threadIdx.x;
    const float4* xr = (const float4*)(x + (size_t)m * MK);  // 512 float4/row
    float4 v0 = xr[t];
    float4 v1 = xr[t + 256];
    float amax = fmaxf(fmaxf(fabsf(v0.x), fabsf(v0.y)),
                       fmaxf(fabsf(v0.z), fabsf(v0.w)));
    amax = fmaxf(amax, fmaxf(fmaxf(fabsf(v1.x), fabsf(v1.y)),
                             fmaxf(fabsf(v1.z), fabsf(v1.w))));
    // wave (64-lane) butterfly reduce
    #pragma unroll
    for (int off = 32; off >= 1; off >>= 1)
        amax = fmaxf(amax, __shfl_xor(amax, off));
    __shared__ float smax[4];
    if ((t & 63) == 0) smax[t >> 6] = amax;
    __syncthreads();
    float a0 = fmaxf(fmaxf(smax[0], smax[1]), fmaxf(smax[2], smax[3]));
    a0 = fmaxf(a0, 1e-5f);                 // clip lower bound
    const float scale = 127.0f / a0;
    if (t == 0) rf[m] = a0 / (127.0f * wscale[0]);

    auto q = [&](float f) -> int {
        float r = rintf(f * scale);        // round-half-to-even
        r = fminf(fmaxf(r, -128.0f), 127.0f);
        return (int)r;
    };
    int p0 = (q(v0.x) & 255) | ((q(v0.y) & 255) << 8) |
             ((q(v0.z) & 255) << 16) | ((q(v0.w) & 255) << 24);
    int p1 = (q(v1.x) & 255) | ((q(v1.y) & 255) << 8) |
             ((q(v1.z) & 255) << 16) | ((q(v1.w) & 255) << 24);
    int* xqr = (int*)(xq + (size_t)m * MK);
    xqr[t]       = p0;
    xqr[t + 256] = p1;
}

// ---------------- weight unpack: [512][2048] packed -> int8 W[2048][2048] ---
// w[i*512 + r][k] = ((packed[r][k] >> 2i) & 3) - 1
__global__ void unpack_kernel(const int* __restrict__ packed,
                              signed char* __restrict__ W) {
    const int idx = blockIdx.x * 256 + threadIdx.x;   // 0 .. 512*512
    const int r  = idx >> 9;        // packed row
    const int kq = idx & 511;       // k/4
    const int4 p = ((const int4*)packed)[idx];        // 4 consecutive k
    int* Wi = (int*)W;              // 512 ints per W row
    #pragma unroll
    for (int i = 0; i < 4; i++) {
        const int sh = 2 * i;
        int b0 = ((((p.x >> sh) & 3) - 1) & 255);
        int b1 = ((((p.y >> sh) & 3) - 1) & 255);
        int b2 = ((((p.z >> sh) & 3) - 1) & 255);
        int b3 = ((((p.w >> sh) & 3) - 1) & 255);
        Wi[(i * 512 + r) * 512 + kq] = b0 | (b1 << 8) | (b2 << 16) | (b3 << 24);
    }
}

// ---------------- int8 GEMM: C[m][n] = sum_k xq[m][k]*W[n][k] --------------
// 128x128 tile, BK=64 bytes, 4 waves in 2x2, 4x4 mfma_i32_16x16x64_i8 each.
// LDS layout per tile row r (64B): 16B chunk c stored at slot c ^ ((r>>1)&3).
__global__ void __launch_bounds__(256)
gemm_kernel(const signed char* __restrict__ xq,   // [M][K]
            const signed char* __restrict__ W,    // [N][K]
            const float* __restrict__ rf,         // [M]
            const float* __restrict__ bias,       // [N]
            float* __restrict__ out) {            // [M][N]
    constexpr int BK = 64;
    __shared__ __attribute__((aligned(16))) unsigned char As[128 * BK];
    __shared__ __attribute__((aligned(16))) unsigned char Bs[128 * BK];

    const int tid  = threadIdx.x;
    const int wave = tid >> 6;
    const int lane = tid & 63;
    const int m0 = blockIdx.y * 128;
    const int n0 = blockIdx.x * 128;

    // staging: chunk cc = 16 rows; lane i -> row cc*16 + i/4, LDS slot i%4.
    // To realize swizzled layout, lane fetches global chunk (i%4)^((row>>1)&3).
    const int srow  = lane >> 2;
    const int sbyte = ((lane & 3) ^ ((srow >> 1) & 3)) * 16;

    const int wm = (wave >> 1) * 64;   // wave's 64x64 subtile
    const int wn = (wave & 1) * 64;
    const int fr = lane & 15;          // fragment row (m or n) low bits
    // fragment k-chunk after un-swizzle: slot = (lane>>4) ^ ((fr>>1)&3)
    const int fslot = ((lane >> 4) ^ ((fr >> 1) & 3)) * 16;

    int4v acc[4][4] = {};

    for (int k0 = 0; k0 < MK; k0 += BK) {
        #pragma unroll
        for (int c = 2 * wave; c < 2 * wave + 2; c++) {
            const signed char* ga =
                xq + (size_t)(m0 + c * 16 + srow) * MK + k0 + sbyte;
            __builtin_amdgcn_global_load_lds((const GLOBAL_AS void*)ga,
                                             (LDS_AS void*)(As + c * 1024),
                                             16, 0, 0);
            const signed char* gb =
                W + (size_t)(n0 + c * 16 + srow) * MK + k0 + sbyte;
            __builtin_amdgcn_global_load_lds((const GLOBAL_AS void*)gb,
                                             (LDS_AS void*)(Bs + c * 1024),
                                             16, 0, 0);
        }
        __syncthreads();

        int4v af[4], bf[4];
        #pragma unroll
        for (int i = 0; i < 4; i++) {
            af[i] = *(const int4v*)(As + (wm + i * 16 + fr) * BK + fslot);
            bf[i] = *(const int4v*)(Bs + (wn + i * 16 + fr) * BK + fslot);
        }
        #pragma unroll
        for (int mt = 0; mt < 4; mt++)
            #pragma unroll
            for (int nt = 0; nt < 4; nt++)
                acc[mt][nt] = __builtin_amdgcn_mfma_i32_16x16x64_i8(
                    af[mt], bf[nt], acc[mt][nt], 0, 0, 0);
        __syncthreads();
    }

    // epilogue: C/D map col=lane&15, row=(lane>>4)*4+reg
    const int col   = lane & 15;
    const int rbase = (lane >> 4) * 4;
    #pragma unroll
    for (int mt = 0; mt < 4; mt++) {
        #pragma unroll
        for (int r = 0; r < 4; r++) {
            const int m = m0 + wm + mt * 16 + rbase + r;
            const float rfm = rf[m];
            #pragma unroll
            for (int nt = 0; nt < 4; nt++) {
                const int n = n0 + wn + nt * 16 + col;
                out[(size_t)m * NN + n] = (float)acc[mt][nt][r] * rfm + bias[n];
            }
        }
    }
}

extern "C" void kernel_launch(void* const* d_in, const int* in_sizes, int n_in,
                              void* d_out, int out_size, void* d_ws, size_t ws_size,
                              hipStream_t stream) {
    const float* x      = (const float*)d_in[0];
    const int*   packed = (const int*)d_in[1];
    const float* wscale = (const float*)d_in[2];
    const float* bias   = (const float*)d_in[3];
    float* out = (float*)d_out;

    // workspace: xq [16384*2048] i8 | W [2048*2048] i8 | rf [16384] f32
    signed char* xq = (signed char*)d_ws;
    signed char* W  = xq + (size_t)MM * MK;
    float*       rf = (float*)(W + (size_t)NN * MK);

    quant_kernel<<<MM, 256, 0, stream>>>(x, wscale, xq, rf);
    unpack_kernel<<<(512 * 512) / 256, 256, 0, stream>>>(packed, W);
    gemm_kernel<<<dim3(NN / 128, MM / 128), 256, 0, stream>>>(xq, W, rf, bias, out);
}